// Round 1
// baseline (118.403 us; speedup 1.0000x reference)
//
#include <hip/hip_runtime.h>

#define H_ 200
#define W_ 200
#define HW_ 40000
#define C_ 256
#define B_ 2
#define P_ 12
#define NBINS 144

// ---------------- Kernel 1: NCHW -> NHWC transpose ----------------
// Tile: 256 pixels x 16 channels. float4 loads along pixels, float4 stores
// along channels. LDS [256][17] (pad 17 to break bank alignment).
__global__ __launch_bounds__(256) void transpose_nchw_nhwc(
    const float* __restrict__ x, float* __restrict__ feat) {
  __shared__ float sT[256 * 17];
  const int t  = threadIdx.x;
  const int p0 = blockIdx.x * 256;
  const int c0 = blockIdx.y * 16;
  const int b  = blockIdx.z;
  const int pcnt = min(256, HW_ - p0);

  const int px4 = t & 63;   // pixel/4 index within tile
  const int crw = t >> 6;   // 0..3
  if (4 * px4 < pcnt) {
#pragma unroll
    for (int cc = 0; cc < 4; ++cc) {
      const int ci = cc * 4 + crw;  // 0..15
      const float4 v = *reinterpret_cast<const float4*>(
          x + (size_t)(b * C_ + c0 + ci) * HW_ + p0 + 4 * px4);
      sT[(4 * px4 + 0) * 17 + ci] = v.x;
      sT[(4 * px4 + 1) * 17 + ci] = v.y;
      sT[(4 * px4 + 2) * 17 + ci] = v.z;
      sT[(4 * px4 + 3) * 17 + ci] = v.w;
    }
  }
  __syncthreads();
  const int c4  = t & 3;    // channel/4 index
  const int prw = t >> 2;   // 0..63
#pragma unroll
  for (int pp = 0; pp < 4; ++pp) {
    const int pi = pp * 64 + prw;
    if (pi < pcnt) {
      float4 w;
      w.x = sT[pi * 17 + 4 * c4 + 0];
      w.y = sT[pi * 17 + 4 * c4 + 1];
      w.z = sT[pi * 17 + 4 * c4 + 2];
      w.w = sT[pi * 17 + 4 * c4 + 3];
      *reinterpret_cast<float4*>(
          feat + (size_t)(b * HW_ + p0 + pi) * C_ + c0 + 4 * c4) = w;
    }
  }
}

// ---------------- Kernel 2: gather + bilinear blend ----------------
// Grid: (C_/64 tiles, N rois). Block: 256 threads = 4 bins x 64 channels.
// Per-bin corner offsets & weights precomputed in LDS (wave-uniform reads).
// Output staged via LDS tile [144][65] so global stores are bin-fastest
// contiguous runs (coalesced into the NCHW output layout).
template <bool NHWC>
__global__ __launch_bounds__(256) void roi_kernel(
    const float* __restrict__ feat, const float* __restrict__ rois,
    float* __restrict__ out, int N) {
  __shared__ float sw0[NBINS], sw1[NBINS], sw2[NBINS], sw3[NBINS];
  __shared__ int so0[NBINS], so1[NBINS], so2[NBINS], so3[NBINS];
  __shared__ float tile[NBINS * 65];

  const int t = threadIdx.x;
  const int n = blockIdx.y;
  const int cbase = blockIdx.x * 64;
  if (n >= N) return;

  if (t < NBINS) {
    const int py = t / P_;
    const int px = t - py * P_;
    const float rb  = rois[n * 5 + 0];
    const float rx1 = rois[n * 5 + 1] * 0.25f;
    const float ry1 = rois[n * 5 + 2] * 0.25f;
    const float rx2 = rois[n * 5 + 3] * 0.25f;
    const float ry2 = rois[n * 5 + 4] * 0.25f;
    const int bi = (int)rb;
    const float bh = (ry2 - ry1) * (1.0f / P_);
    const float bw = (rx2 - rx1) * (1.0f / P_);
    float ys = ry1 + ((float)py + 0.5f) * bh;
    float xs = rx1 + ((float)px + 0.5f) * bw;
    ys = fminf(fmaxf(ys, 0.0f), (float)(H_ - 1));
    xs = fminf(fmaxf(xs, 0.0f), (float)(W_ - 1));
    const float y0f = floorf(ys);
    const float x0f = floorf(xs);
    const float ly = ys - y0f;
    const float lx = xs - x0f;
    const int y0 = (int)y0f;
    const int x0 = (int)x0f;
    const int y1 = min(y0 + 1, H_ - 1);
    const int x1 = min(x0 + 1, W_ - 1);
    sw0[t] = (1.0f - ly) * (1.0f - lx);
    sw1[t] = (1.0f - ly) * lx;
    sw2[t] = ly * (1.0f - lx);
    sw3[t] = ly * lx;
    if (NHWC) {
      const int pb = bi * HW_;
      so0[t] = (pb + y0 * W_ + x0) * C_;
      so1[t] = (pb + y0 * W_ + x1) * C_;
      so2[t] = (pb + y1 * W_ + x0) * C_;
      so3[t] = (pb + y1 * W_ + x1) * C_;
    } else {
      const int pb = bi * C_ * HW_;
      so0[t] = pb + y0 * W_ + x0;
      so1[t] = pb + y0 * W_ + x1;
      so2[t] = pb + y1 * W_ + x0;
      so3[t] = pb + y1 * W_ + x1;
    }
  }
  __syncthreads();

  const int c  = t & 63;   // channel within tile
  const int bq = t >> 6;   // bin sub-group 0..3 (one wave per bin)
  const float* fb = NHWC ? (feat + cbase) : (feat + (size_t)cbase * HW_);
  const int coff = NHWC ? c : c * HW_;
#pragma unroll 4
  for (int it = 0; it < 36; ++it) {
    const int bin = it * 4 + bq;  // wave-uniform
    const float v = sw0[bin] * fb[so0[bin] + coff] +
                    sw1[bin] * fb[so1[bin] + coff] +
                    sw2[bin] * fb[so2[bin] + coff] +
                    sw3[bin] * fb[so3[bin] + coff];
    tile[bin * 65 + c] = v;
  }
  __syncthreads();

  float* ob = out + ((size_t)n * C_ + cbase) * NBINS;
#pragma unroll
  for (int i = 0; i < 36; ++i) {
    const int idx = i * 256 + t;       // 0..9215
    const int cc = idx / NBINS;        // 0..63
    const int bb = idx - cc * NBINS;   // 0..143
    ob[cc * NBINS + bb] = tile[bb * 65 + cc];
  }
}

extern "C" void kernel_launch(void* const* d_in, const int* in_sizes, int n_in,
                              void* d_out, int out_size, void* d_ws,
                              size_t ws_size, hipStream_t stream) {
  const float* x    = (const float*)d_in[0];
  const float* rois = (const float*)d_in[1];
  float* out = (float*)d_out;
  float* ws  = (float*)d_ws;
  const int N = in_sizes[1] / 5;

  const size_t need = (size_t)B_ * C_ * HW_ * sizeof(float);
  if (ws_size >= need) {
    // 40000 pixels / 256 per tile -> 157 tiles; 256 ch / 16 -> 16 tiles; B=2
    transpose_nchw_nhwc<<<dim3(157, 16, 2), 256, 0, stream>>>(x, ws);
    roi_kernel<true><<<dim3(C_ / 64, N), 256, 0, stream>>>(ws, rois, out, N);
  } else {
    roi_kernel<false><<<dim3(C_ / 64, N), 256, 0, stream>>>(x, rois, out, N);
  }
}